// Round 5
// baseline (176.187 us; speedup 1.0000x reference)
//
#include <hip/hip_runtime.h>
#include <hip/hip_cooperative_groups.h>

namespace cg = cooperative_groups;

#define NB 256
#define CLIP_LIM 1024              // max(int(4.0*65536/256),1)
#define HSTRIDE 264                // sub-hist stride: shifts bank pattern by 8 per table
#define NSUB 16                    // 2 sub-histograms per wave (lane parity), 8 waves
#define NTH 512                    // threads per fused block
#define PW 3                       // padded x-table width (cols tx-1,tx,tx+1), gcd(3,32)=1
#define PROW (NB*PW)               // 768 floats per y-row table

typedef float f32x4 __attribute__((ext_vector_type(4)));

// ================= fused cooperative kernel: one block per tile =================
// Phase 1: histogram (bins kept in registers) -> clip -> redistribute -> scan -> LUT to global
// grid.sync()
// Phase 2: 9 neighbor LUTs -> LDS padded tables -> exact bilinear apply from register bins
__global__ __launch_bounds__(NTH, 4) void clahe_fused(const float* __restrict__ img,
                                                      float* __restrict__ lut,
                                                      float* __restrict__ out) {
    const int t   = blockIdx.x;          // b*64 + ty*8 + tx
    const int b   = t >> 6;
    const int ty  = (t >> 3) & 7;
    const int tx  = t & 7;
    const int tid = threadIdx.x;
    const int sub = ((tid >> 6) << 1) | (tid & 1);   // 0..15

    __shared__ int   h[NSUB * HSTRIDE];  // 16,896 B
    __shared__ int   c[NB];
    __shared__ int   s_excess;
    __shared__ float P[3 * PROW];        // 9,216 B : P[yrow][bin*3+kx]

    #pragma unroll
    for (int k = 0; k < 9; ++k) {
        const int idx = tid + k * NTH;
        if (idx < NSUB * HSTRIDE) h[idx] = 0;
    }
    if (tid == 0) s_excess = 0;
    __syncthreads();

    const size_t tbase = ((size_t)b << 22) + (size_t)(ty * 256) * 2048 + tx * 256;
    const float* base = img + tbase;
    int* hw = &h[sub * HSTRIDE];

    // ---- phase 1: 16384 float4 per tile, 32 iters; bins stay in registers
    unsigned int breg[32];
    #pragma unroll
    for (int k = 0; k < 32; ++k) {
        const int i = tid + k * NTH;
        const int r = i >> 6;            // tile row 0..255
        const int q = i & 63;            // float4 column
        const f32x4 v = __builtin_nontemporal_load(
            reinterpret_cast<const f32x4*>(base + (size_t)r * 2048 + q * 4));
        const int b0 = (int)fminf(fmaxf(v.x, 0.f), 255.f);
        const int b1 = (int)fminf(fmaxf(v.y, 0.f), 255.f);
        const int b2 = (int)fminf(fmaxf(v.z, 0.f), 255.f);
        const int b3 = (int)fminf(fmaxf(v.w, 0.f), 255.f);
        atomicAdd(&hw[b0], 1);
        atomicAdd(&hw[b1], 1);
        atomicAdd(&hw[b2], 1);
        atomicAdd(&hw[b3], 1);
        breg[k] = (unsigned)b0 | ((unsigned)b1 << 8) | ((unsigned)b2 << 16) | ((unsigned)b3 << 24);
    }
    __syncthreads();

    int clipped = 0;
    if (tid < NB) {
        int sum = 0;
        #pragma unroll
        for (int w = 0; w < NSUB; ++w) sum += h[w * HSTRIDE + tid];
        clipped = min(sum, CLIP_LIM);
        atomicAdd(&s_excess, sum - clipped);
    }
    __syncthreads();

    if (tid < NB) {
        const int excess   = s_excess;
        const int add      = excess >> 8;
        const int residual = excess & 255;
        int step = 256 / (residual > 0 ? residual : 1);
        if (step < 1) step = 1;
        c[tid] = clipped + add + ((residual > 0 && (tid % step) == 0) ? 1 : 0);
    }
    __syncthreads();

    #pragma unroll
    for (int off = 1; off < NB; off <<= 1) {
        int v = 0;
        if (tid < NB && tid >= off) v = c[tid - off];
        __syncthreads();
        if (tid < NB) c[tid] += v;
        __syncthreads();
    }

    if (tid < NB) {
        float lv = rintf((float)c[tid] * (255.0f / 65536.0f));   // exact; RTE == jnp.round
        lut[t * NB + tid] = fminf(fmaxf(lv, 0.f), 255.f);
    }

    __threadfence();
    cg::this_grid().sync();

    // ---- phase 2: stage 9 neighbor LUTs as padded x-tables
    if (tid < NB) {
        const float* lb = lut + ((size_t)b << 14);
        #pragma unroll
        for (int ry = 0; ry < 3; ++ry) {
            const int rr = min(max(ty - 1 + ry, 0), 7);
            #pragma unroll
            for (int kx = 0; kx < 3; ++kx) {
                const int cc = min(max(tx - 1 + kx, 0), 7);
                P[ry * PROW + tid * PW + kx] = lb[(rr * 8 + cc) * NB + tid];
            }
        }
    }
    __syncthreads();

    // lane-constant x params: xl = (tid&63)*4; s_x = xl>=128; xa_j = ((xl+j+128)&255)/256
    const int xl   = (tid & 63) * 4;
    const int s_x  = (xl >= 128) ? 1 : 0;
    const float xa0 = (float)((xl + 128) & 255);     // numerator; no wrap within j=0..3

    float* outp = out + tbase;
    #pragma unroll
    for (int k = 0; k < 32; ++k) {
        const int i  = tid + k * NTH;
        const int r  = i >> 6;                       // tile row (wave-uniform)
        const int sy = (r >= 128) ? 1 : 0;
        const float ya = (float)((r + 128) & 255) * (1.0f / 256.0f);
        const float* P0 = &P[sy * PROW];
        const float* P1 = &P[(sy + 1) * PROW];
        const unsigned int w = breg[k];
        float res[4];
        #pragma unroll
        for (int j = 0; j < 4; ++j) {
            const int bn  = (w >> (8 * j)) & 255;
            const int idx = bn * 3 + s_x;
            const float l11 = P0[idx];
            const float l12 = P0[idx + 1];           // ds_read2_b32 pair
            const float l21 = P1[idx];
            const float l22 = P1[idx + 1];
            const float xa  = (xa0 + (float)j) * (1.0f / 256.0f);
            const float top = l11 + (l12 - l11) * xa;    // exact
            const float bot = l21 + (l22 - l21) * xa;    // exact
            const float v   = top + (bot - top) * ya;    // exact
            res[j] = fminf(fmaxf(rintf(v), 0.f), 255.f);
        }
        const f32x4 o = { res[0], res[1], res[2], res[3] };
        __builtin_nontemporal_store(o, reinterpret_cast<f32x4*>(outp + (size_t)r * 2048 + xl));
    }
}

// ================= fallback: proven two-kernel path (R4) =================
__global__ __launch_bounds__(1024) void clahe_hist_lut(const float* __restrict__ img,
                                                       float* __restrict__ lut,
                                                       unsigned int* __restrict__ bins) {
    const int t   = blockIdx.x;
    const int b   = t >> 6;
    const int ty  = (t >> 3) & 7;
    const int tx  = t & 7;
    const int tid = threadIdx.x;
    const int sub = ((tid >> 6) << 1) | (tid & 1);

    __shared__ int h[32 * HSTRIDE];
    __shared__ int c[NB];
    __shared__ int s_excess;

    #pragma unroll
    for (int k = 0; k < 9; ++k) {
        const int idx = tid + k * 1024;
        if (idx < 32 * HSTRIDE) h[idx] = 0;
    }
    if (tid == 0) s_excess = 0;
    __syncthreads();

    const float* base = img + ((size_t)b << 22) + (size_t)(ty * 256) * 2048 + tx * 256;
    unsigned int* bbase = bins + ((size_t)b << 20) + ty * 131072 + tx * 64;
    int* hw = &h[sub * HSTRIDE];

    for (int i = tid; i < 16384; i += 1024) {
        const int r = i >> 6;
        const int q = i & 63;
        const f32x4 v = __builtin_nontemporal_load(
            reinterpret_cast<const f32x4*>(base + (size_t)r * 2048 + q * 4));
        const int b0 = (int)fminf(fmaxf(v.x, 0.f), 255.f);
        const int b1 = (int)fminf(fmaxf(v.y, 0.f), 255.f);
        const int b2 = (int)fminf(fmaxf(v.z, 0.f), 255.f);
        const int b3 = (int)fminf(fmaxf(v.w, 0.f), 255.f);
        atomicAdd(&hw[b0], 1);
        atomicAdd(&hw[b1], 1);
        atomicAdd(&hw[b2], 1);
        atomicAdd(&hw[b3], 1);
        bbase[r * 512 + q] = (unsigned)b0 | ((unsigned)b1 << 8) |
                             ((unsigned)b2 << 16) | ((unsigned)b3 << 24);
    }
    __syncthreads();

    int clipped = 0;
    if (tid < NB) {
        int sum = 0;
        #pragma unroll
        for (int w = 0; w < 32; ++w) sum += h[w * HSTRIDE + tid];
        clipped = min(sum, CLIP_LIM);
        atomicAdd(&s_excess, sum - clipped);
    }
    __syncthreads();

    if (tid < NB) {
        const int excess   = s_excess;
        const int add      = excess >> 8;
        const int residual = excess & 255;
        int step = 256 / (residual > 0 ? residual : 1);
        if (step < 1) step = 1;
        c[tid] = clipped + add + ((residual > 0 && (tid % step) == 0) ? 1 : 0);
    }
    __syncthreads();

    #pragma unroll
    for (int off = 1; off < NB; off <<= 1) {
        int v = 0;
        if (tid < NB && tid >= off) v = c[tid - off];
        __syncthreads();
        if (tid < NB) c[tid] += v;
        __syncthreads();
    }

    if (tid < NB) {
        float lv = rintf((float)c[tid] * (255.0f / 65536.0f));
        lut[t * NB + tid] = fminf(fmaxf(lv, 0.f), 255.f);
    }
}

#define TSTRIDE 11
__global__ __launch_bounds__(256) void clahe_apply(const unsigned int* __restrict__ bins,
                                                   const float* __restrict__ lut,
                                                   float* __restrict__ out) {
    const int bi  = blockIdx.x;
    const int b   = bi >> 9;
    const int y0  = (bi & 511) * 4;
    const int tid = threadIdx.x;

    __shared__ float T[4 * NB * TSTRIDE];

    {
        const float yf  = (float)y0 * (1.0f / 256.0f) - 0.5f;
        const float y1f = floorf(yf);
        const int y1 = min(max((int)y1f, 0), 7);
        const int y2 = min(max((int)y1f + 1, 0), 7);
        const float* lb = lut + ((size_t)b << 14);
        float la[8], lc[8];
        #pragma unroll
        for (int xc = 0; xc < 8; ++xc) {
            la[xc] = lb[(y1 * 8 + xc) * NB + tid];
            lc[xc] = lb[(y2 * 8 + xc) * NB + tid];
        }
        #pragma unroll
        for (int r = 0; r < 4; ++r) {
            const float yfr = (float)(y0 + r) * (1.0f / 256.0f) - 0.5f;
            const float ya  = yfr - floorf(yfr);
            float* Tr = &T[r * NB * TSTRIDE + tid * TSTRIDE];
            #pragma unroll
            for (int kk = 0; kk < 10; ++kk) {
                const int kc = (kk == 0) ? 0 : ((kk - 1 > 7) ? 7 : kk - 1);
                Tr[kk] = la[kc] * (1.0f - ya) + lc[kc] * ya;
            }
        }
    }
    __syncthreads();

    const size_t imgbase = ((size_t)b << 22) + (size_t)y0 * 2048;
    #pragma unroll
    for (int it = 0; it < 8; ++it) {
        const int r = it >> 1;
        const int i = (it & 1) * 256 + tid;
        const size_t prow = imgbase + (size_t)r * 2048;
        const unsigned int w = bins[(prow >> 2) + i];
        const float* Tr = &T[r * NB * TSTRIDE];
        float res[4];
        #pragma unroll
        for (int j = 0; j < 4; ++j) {
            const int x    = i * 4 + j;
            const float xf = (float)x * (1.0f / 256.0f) - 0.5f;
            const float fl = floorf(xf);
            const float xa = xf - fl;
            const int s    = (int)fl + 1;
            const int bn   = (w >> (8 * j)) & 255;
            const float* p = &Tr[bn * TSTRIDE + s];
            const float a  = p[0];
            const float b2 = p[1];
            const float v  = a + (b2 - a) * xa;
            res[j] = fminf(fmaxf(rintf(v), 0.f), 255.f);
        }
        const f32x4 o = { res[0], res[1], res[2], res[3] };
        __builtin_nontemporal_store(o, reinterpret_cast<f32x4*>(out + prow + i * 4));
    }
}

extern "C" void kernel_launch(void* const* d_in, const int* in_sizes, int n_in,
                              void* d_out, int out_size, void* d_ws, size_t ws_size,
                              hipStream_t stream) {
    const float* img = (const float*)d_in[0];
    float* out = (float*)d_out;
    float* lut = (float*)d_ws;                                    // 512 KiB
    unsigned int* bins = (unsigned int*)((char*)d_ws + 512 * 1024);

    void* args[] = { (void*)&img, (void*)&lut, (void*)&out };
    hipError_t err = hipLaunchCooperativeKernel((const void*)clahe_fused,
                                                dim3(512), dim3(NTH), args, 0, stream);
    if (err != hipSuccess) {
        // fallback: proven two-kernel path (identical output)
        clahe_hist_lut<<<512, 1024, 0, stream>>>(img, lut, bins);
        clahe_apply<<<8 * 512, 256, 0, stream>>>(bins, lut, out);
    }
}

// Round 6
// 78.335 us; speedup vs baseline: 2.2491x; 2.2491x over previous
//
#include <hip/hip_runtime.h>

#define NB 256
#define CLIP_LIM 1024              // max(int(4.0*65536/256),1)
#define HSTRIDE 264                // 256+8: adjacent sub-hists shift bank pattern by 8
#define NSUB 32                    // 2 sub-histograms per wave (lane parity), 16 waves
#define PSTRIDE 9                  // packed u16-pair entries per bin (s=0..8), gcd(9,32)=1

typedef float f32x4 __attribute__((ext_vector_type(4)));

// ---------------- Kernel 1: per-tile histogram -> clip/redistribute -> cdf -> LUT (+ packed u8 bins)
// 1024 thr/block, 34.8KB LDS -> 2 blocks/CU = 32 waves/CU (launch_bounds caps VGPR at 64)
__global__ __launch_bounds__(1024, 8) void clahe_hist_lut(const float* __restrict__ img,
                                                          float* __restrict__ lut,
                                                          unsigned int* __restrict__ bins) {
    const int t   = blockIdx.x;          // 0..511  (b*64 + ty*8 + tx)
    const int b   = t >> 6;
    const int ty  = (t >> 3) & 7;
    const int tx  = t & 7;
    const int tid = threadIdx.x;
    const int sub = ((tid >> 6) << 1) | (tid & 1);   // 0..31: wave*2 + lane parity

    __shared__ int h[NSUB * HSTRIDE];    // 33,792 B
    __shared__ int c[NB];
    __shared__ int s_excess;

    #pragma unroll
    for (int k = 0; k < 9; ++k) {
        const int idx = tid + k * 1024;
        if (idx < NSUB * HSTRIDE) h[idx] = 0;
    }
    if (tid == 0) s_excess = 0;
    __syncthreads();

    const float* base = img + ((size_t)b << 22) + (size_t)(ty * 256) * 2048 + tx * 256;
    unsigned int* bbase = bins + ((size_t)b << 20) + ty * 131072 + tx * 64;
    int* hw = &h[sub * HSTRIDE];

    // 16384 float4 per tile; 16 iterations of 1024 threads, coalesced; regular loads (L2/L3 allocate)
    for (int i = tid; i < 16384; i += 1024) {
        const int r = i >> 6;            // tile row 0..255
        const int q = i & 63;            // float4 column
        const f32x4 v = *reinterpret_cast<const f32x4*>(base + (size_t)r * 2048 + q * 4);
        const int b0 = (int)fminf(fmaxf(v.x, 0.f), 255.f);
        const int b1 = (int)fminf(fmaxf(v.y, 0.f), 255.f);
        const int b2 = (int)fminf(fmaxf(v.z, 0.f), 255.f);
        const int b3 = (int)fminf(fmaxf(v.w, 0.f), 255.f);
        atomicAdd(&hw[b0], 1);
        atomicAdd(&hw[b1], 1);
        atomicAdd(&hw[b2], 1);
        atomicAdd(&hw[b3], 1);
        bbase[r * 512 + q] = (unsigned)b0 | ((unsigned)b1 << 8) |
                             ((unsigned)b2 << 16) | ((unsigned)b3 << 24);
    }
    __syncthreads();

    // merge 32 sub-histograms, clip, accumulate excess
    int clipped = 0;
    if (tid < NB) {
        int sum = 0;
        #pragma unroll
        for (int w = 0; w < NSUB; ++w) sum += h[w * HSTRIDE + tid];
        clipped = min(sum, CLIP_LIM);
        atomicAdd(&s_excess, sum - clipped);
    }
    __syncthreads();

    if (tid < NB) {
        const int excess   = s_excess;
        const int add      = excess >> 8;
        const int residual = excess & 255;
        int step = 256 / (residual > 0 ? residual : 1);
        if (step < 1) step = 1;
        c[tid] = clipped + add + ((residual > 0 && (tid % step) == 0) ? 1 : 0);
    }
    __syncthreads();

    // inclusive Hillis-Steele scan over 256 bins (all threads hit barriers)
    #pragma unroll
    for (int off = 1; off < NB; off <<= 1) {
        int v = 0;
        if (tid < NB && tid >= off) v = c[tid - off];
        __syncthreads();
        if (tid < NB) c[tid] += v;
        __syncthreads();
    }

    if (tid < NB) {
        float lv = rintf((float)c[tid] * (255.0f / 65536.0f));  // exact; RTE matches jnp.round
        lut[t * NB + tid] = fminf(fmaxf(lv, 0.f), 255.f);
    }
}

// ---------------- Kernel 2: bilinear LUT apply via packed fixed-point 8.8 LDS tables
// Block = (image, 2-row group); 18.4KB LDS -> 8 blocks/CU = 32 waves/CU.
// T[r][bin][s] = pack_u32(t[s]*256, t[s+1]*256) where t[k] = y-blended LUT of x-col clip(k-1,0,7);
// table values are multiples of 1/256 <= 255 -> *256 is an exact integer <= 65280 (fits u16).
// Per pixel: ONE ds_read_b32 + exact f32 x-blend (all numerators < 2^24) -> bit-exact vs ref.
__global__ __launch_bounds__(256, 8) void clahe_apply(const unsigned int* __restrict__ bins,
                                                      const float* __restrict__ lut,
                                                      float* __restrict__ out) {
    const int bi  = blockIdx.x;
    const int b   = bi >> 10;
    const int y0  = (bi & 1023) * 2;     // even row pair; never straddles a y-segment boundary
    const int tid = threadIdx.x;

    __shared__ unsigned int T[2 * NB * PSTRIDE];   // 18,432 B

    {   // ---- build packed y-blended tables for both rows (tid == bin)
        const float yf  = (float)y0 * (1.0f / 256.0f) - 0.5f;
        const float y1f = floorf(yf);
        const int y1 = min(max((int)y1f, 0), 7);
        const int y2 = min(max((int)y1f + 1, 0), 7);
        const float* lb = lut + ((size_t)b << 14);
        float la[8], lc[8];
        #pragma unroll
        for (int xc = 0; xc < 8; ++xc) {
            la[xc] = lb[(y1 * 8 + xc) * NB + tid];
            lc[xc] = lb[(y2 * 8 + xc) * NB + tid];
        }
        #pragma unroll
        for (int r = 0; r < 2; ++r) {
            const float q = (float)((y0 + r + 128) & 255);   // ya*256, integer
            float tv[10];
            #pragma unroll
            for (int k = 0; k < 10; ++k) {
                const int kc = (k == 0) ? 0 : ((k - 1 > 7) ? 7 : k - 1);
                tv[k] = la[kc] * (256.0f - q) + lc[kc] * q;  // exact integer <= 65280
            }
            unsigned int* Tr = &T[r * NB * PSTRIDE + tid * PSTRIDE];
            #pragma unroll
            for (int s = 0; s < 9; ++s)
                Tr[s] = (unsigned int)tv[s] | ((unsigned int)tv[s + 1] << 16);
        }
    }
    __syncthreads();

    const size_t imgbase = ((size_t)b << 22) + (size_t)y0 * 2048;
    #pragma unroll
    for (int it = 0; it < 4; ++it) {
        const int r = it >> 1;
        const int i = (it & 1) * 256 + tid;          // float4-word index in row, 0..511
        const size_t prow = imgbase + (size_t)r * 2048;
        const unsigned int w = bins[(prow >> 2) + i];
        const unsigned int* Tr = &T[r * NB * PSTRIDE];
        const int x   = i * 4;
        const int s   = (x + 128) >> 8;              // 0..8, constant within quad
        const float xa0 = (float)((x + 128) & 255);  // numerator; no wrap within j=0..3
        float res[4];
        #pragma unroll
        for (int j = 0; j < 4; ++j) {
            const int bn = (w >> (8 * j)) & 255;
            const unsigned int u = Tr[bn * PSTRIDE + s];      // one ds_read_b32
            const float a  = (float)(u & 0xFFFFu);            // left*256 (exact int)
            const float bb = (float)(u >> 16);                // right*256 (exact int)
            const float xa = (xa0 + (float)j) * (1.0f / 256.0f);
            const float v  = a + (bb - a) * xa;               // exact, = result*256
            res[j] = fminf(fmaxf(rintf(v * (1.0f / 256.0f)), 0.f), 255.f);
        }
        const f32x4 o = { res[0], res[1], res[2], res[3] };
        __builtin_nontemporal_store(o, reinterpret_cast<f32x4*>(out + prow + i * 4));
    }
}

extern "C" void kernel_launch(void* const* d_in, const int* in_sizes, int n_in,
                              void* d_out, int out_size, void* d_ws, size_t ws_size,
                              hipStream_t stream) {
    const float* img = (const float*)d_in[0];
    float* out = (float*)d_out;
    float* lut = (float*)d_ws;                                    // 512 KiB
    unsigned int* bins = (unsigned int*)((char*)d_ws + 512 * 1024);

    clahe_hist_lut<<<512, 1024, 0, stream>>>(img, lut, bins);
    clahe_apply<<<8 * 1024, 256, 0, stream>>>(bins, lut, out);
}

// Round 7
// 68.060 us; speedup vs baseline: 2.5887x; 1.1510x over previous
//
#include <hip/hip_runtime.h>

#define NB 256
#define CLIP_LIM 1024              // max(int(4.0*65536/256),1)
#define HSTRIDE 264                // 256+8: adjacent sub-hists shift bank pattern by 8
#define PSTRIDE 9                  // packed u16-pair entries per bin (s=0..8), gcd(9,32)=1

typedef float f32x4 __attribute__((ext_vector_type(4)));

// ---------------- Kernel 1: LINEAR histogram pass ----------------
// 512 blocks x 1024 thr; 8 blocks per (b,ty) band (2MB contiguous). Each block reads a
// contiguous 256KB span. Aligned 64-quad wave reads (256px) lie in ONE tile column, and
// wave w always serves tx = w&7 -> wave-private sub-hists (parity split -> 32 tables).
// Outputs: packed u8 bins (image-linear, coalesced) + per-block partial hists (no atomics).
__global__ __launch_bounds__(1024) void clahe_hist(const float* __restrict__ img,
                                                   unsigned int* __restrict__ bins,
                                                   unsigned int* __restrict__ part) {
    const int blk  = blockIdx.x;         // 0..511
    const int tid  = threadIdx.x;
    const int sub  = ((tid >> 6) << 1) | (tid & 1);   // 0..31: wave*2 + lane parity

    __shared__ int h[32 * HSTRIDE];      // 33,792 B

    #pragma unroll
    for (int k = 0; k < 9; ++k) {
        const int idx = tid + k * 1024;
        if (idx < 32 * HSTRIDE) h[idx] = 0;
    }
    __syncthreads();

    const size_t B0 = (size_t)blk * 16384;    // base quad index (band*131072 + j*16384)
    int* hw = &h[sub * HSTRIDE];

    #pragma unroll
    for (int k = 0; k < 16; ++k) {
        const size_t g = B0 + k * 1024 + tid;           // image-linear quad index
        const f32x4 v = __builtin_nontemporal_load(
            reinterpret_cast<const f32x4*>(img + g * 4));    // linear, read-once
        const int b0 = (int)fminf(fmaxf(v.x, 0.f), 255.f);
        const int b1 = (int)fminf(fmaxf(v.y, 0.f), 255.f);
        const int b2 = (int)fminf(fmaxf(v.z, 0.f), 255.f);
        const int b3 = (int)fminf(fmaxf(v.w, 0.f), 255.f);
        atomicAdd(&hw[b0], 1);
        atomicAdd(&hw[b1], 1);
        atomicAdd(&hw[b2], 1);
        atomicAdd(&hw[b3], 1);
        bins[g] = (unsigned)b0 | ((unsigned)b1 << 8) |
                  ((unsigned)b2 << 16) | ((unsigned)b3 << 24);   // linear, coalesced
    }
    __syncthreads();

    // write partials: 8 tile-columns x 256 bins; tables for tx: {2tx,2tx+1,2tx+16,2tx+17}
    #pragma unroll
    for (int e = tid; e < 2048; e += 1024) {
        const int tx = e >> 8;
        const int bn = e & 255;
        const int s = h[(2 * tx) * HSTRIDE + bn] + h[(2 * tx + 1) * HSTRIDE + bn] +
                      h[(2 * tx + 16) * HSTRIDE + bn] + h[(2 * tx + 17) * HSTRIDE + bn];
        part[(size_t)blk * 2048 + e] = (unsigned int)s;          // coalesced
    }
}

// ---------------- Kernel 1b: reduce partials -> clip/redistribute -> scan -> LUT ----------------
__global__ __launch_bounds__(256) void clahe_lut(const unsigned int* __restrict__ part,
                                                 float* __restrict__ lut) {
    const int t    = blockIdx.x;         // tile = band*8 + tx = b*64 + ty*8 + tx
    const int band = t >> 3;
    const int tx   = t & 7;
    const int tid  = threadIdx.x;        // bin

    __shared__ int c[NB];
    __shared__ int s_excess;
    if (tid == 0) s_excess = 0;
    __syncthreads();

    int sum = 0;
    #pragma unroll
    for (int j = 0; j < 8; ++j)
        sum += (int)part[(size_t)(band * 8 + j) * 2048 + tx * 256 + tid];

    const int clipped0 = min(sum, CLIP_LIM);
    atomicAdd(&s_excess, sum - clipped0);
    __syncthreads();

    const int excess   = s_excess;
    const int add      = excess >> 8;
    const int residual = excess & 255;
    int step = 256 / (residual > 0 ? residual : 1);
    if (step < 1) step = 1;
    c[tid] = clipped0 + add + ((residual > 0 && (tid % step) == 0) ? 1 : 0);
    __syncthreads();

    // inclusive Hillis-Steele scan over 256 bins
    #pragma unroll
    for (int off = 1; off < NB; off <<= 1) {
        const int v = (tid >= off) ? c[tid - off] : 0;
        __syncthreads();
        c[tid] += v;
        __syncthreads();
    }

    float lv = rintf((float)c[tid] * (255.0f / 65536.0f));   // exact; RTE == jnp.round
    lut[t * NB + tid] = fminf(fmaxf(lv, 0.f), 255.f);
}

// ---------------- Kernel 2: bilinear LUT apply (unchanged from R6) ----------------
// Block = (image, even row pair); packed fixed-point 8.8 tables; ONE ds_read_b32 per pixel.
// All f32 arithmetic exact (integers x k/256 weights, numerators < 2^24) -> bit-exact vs ref.
__global__ __launch_bounds__(256, 8) void clahe_apply(const unsigned int* __restrict__ bins,
                                                      const float* __restrict__ lut,
                                                      float* __restrict__ out) {
    const int bi  = blockIdx.x;
    const int b   = bi >> 10;
    const int y0  = (bi & 1023) * 2;     // even row pair; never straddles a y-segment boundary
    const int tid = threadIdx.x;

    __shared__ unsigned int T[2 * NB * PSTRIDE];   // 18,432 B

    {   // ---- build packed y-blended tables for both rows (tid == bin)
        const float yf  = (float)y0 * (1.0f / 256.0f) - 0.5f;
        const float y1f = floorf(yf);
        const int y1 = min(max((int)y1f, 0), 7);
        const int y2 = min(max((int)y1f + 1, 0), 7);
        const float* lb = lut + ((size_t)b << 14);
        float la[8], lc[8];
        #pragma unroll
        for (int xc = 0; xc < 8; ++xc) {
            la[xc] = lb[(y1 * 8 + xc) * NB + tid];
            lc[xc] = lb[(y2 * 8 + xc) * NB + tid];
        }
        #pragma unroll
        for (int r = 0; r < 2; ++r) {
            const float q = (float)((y0 + r + 128) & 255);   // ya*256, integer
            float tv[10];
            #pragma unroll
            for (int k = 0; k < 10; ++k) {
                const int kc = (k == 0) ? 0 : ((k - 1 > 7) ? 7 : k - 1);
                tv[k] = la[kc] * (256.0f - q) + lc[kc] * q;  // exact integer <= 65280
            }
            unsigned int* Tr = &T[r * NB * PSTRIDE + tid * PSTRIDE];
            #pragma unroll
            for (int s = 0; s < 9; ++s)
                Tr[s] = (unsigned int)tv[s] | ((unsigned int)tv[s + 1] << 16);
        }
    }
    __syncthreads();

    const size_t imgbase = ((size_t)b << 22) + (size_t)y0 * 2048;
    #pragma unroll
    for (int it = 0; it < 4; ++it) {
        const int r = it >> 1;
        const int i = (it & 1) * 256 + tid;          // float4-word index in row, 0..511
        const size_t prow = imgbase + (size_t)r * 2048;
        const unsigned int w = bins[(prow >> 2) + i];
        const unsigned int* Tr = &T[r * NB * PSTRIDE];
        const int x   = i * 4;
        const int s   = (x + 128) >> 8;              // 0..8, constant within quad
        const float xa0 = (float)((x + 128) & 255);  // numerator; no wrap within j=0..3
        float res[4];
        #pragma unroll
        for (int j = 0; j < 4; ++j) {
            const int bn = (w >> (8 * j)) & 255;
            const unsigned int u = Tr[bn * PSTRIDE + s];      // one ds_read_b32
            const float a  = (float)(u & 0xFFFFu);            // left*256 (exact int)
            const float bb = (float)(u >> 16);                // right*256 (exact int)
            const float xa = (xa0 + (float)j) * (1.0f / 256.0f);
            const float v  = a + (bb - a) * xa;               // exact, = result*256
            res[j] = fminf(fmaxf(rintf(v * (1.0f / 256.0f)), 0.f), 255.f);
        }
        const f32x4 o = { res[0], res[1], res[2], res[3] };
        __builtin_nontemporal_store(o, reinterpret_cast<f32x4*>(out + prow + i * 4));
    }
}

extern "C" void kernel_launch(void* const* d_in, const int* in_sizes, int n_in,
                              void* d_out, int out_size, void* d_ws, size_t ws_size,
                              hipStream_t stream) {
    const float* img = (const float*)d_in[0];
    float* out = (float*)d_out;
    float* lut = (float*)d_ws;                                            // 512 KiB
    unsigned int* bins = (unsigned int*)((char*)d_ws + 512 * 1024);       // 33.5 MB
    unsigned int* part = (unsigned int*)((char*)d_ws + 512 * 1024 + 33554432);  // 4 MB

    clahe_hist<<<512, 1024, 0, stream>>>(img, bins, part);
    clahe_lut<<<512, 256, 0, stream>>>(part, lut);
    clahe_apply<<<8 * 1024, 256, 0, stream>>>(bins, lut, out);
}